// Round 6
// baseline (1282.221 us; speedup 1.0000x reference)
//
#include <hip/hip_runtime.h>
#include <math.h>

#define NDIM 128      // feature dim (D == H == 128)

typedef __attribute__((ext_vector_type(8))) short short8;
typedef __attribute__((ext_vector_type(4))) float f32x4;

__device__ __forceinline__ float sigmoidf_(float x){ return 1.0f/(1.0f + __expf(-x)); }

// f32 -> bf16 (round-to-nearest-even)
__device__ __forceinline__ unsigned short f2bf(float f){
  unsigned u = __float_as_uint(f);
  unsigned r = (u + 0x7fffu + ((u >> 16) & 1u)) >> 16;
  return (unsigned short)r;
}

// ---- degree / normalization ----
__global__ void deg_count_k(const int* __restrict__ dst, int* __restrict__ counts, int E){
  int e = blockIdx.x*blockDim.x + threadIdx.x;
  if(e < E) atomicAdd(&counts[dst[e]], 1);
}

__global__ void dinv_k(const int* __restrict__ counts, float* __restrict__ dinv, int N){
  int i = blockIdx.x*blockDim.x + threadIdx.x;
  if(i < N) dinv[i] = rsqrtf(1.0f + (float)counts[i]);
}

// ---- 3-kernel exclusive prefix scan over counts (chunk = 256) ----
__global__ void scan1_k(const int* __restrict__ counts, int* __restrict__ scanned,
                        int* __restrict__ chunksums, int N){
  __shared__ int lds[256];
  int t = threadIdx.x; int idx = blockIdx.x*256 + t;
  int x = (idx < N) ? counts[idx] : 0;
  lds[t] = x; __syncthreads();
  for(int o=1;o<256;o<<=1){
    int v = (t>=o) ? lds[t-o] : 0;
    __syncthreads();
    lds[t] += v;
    __syncthreads();
  }
  if(idx < N) scanned[idx] = lds[t];
  if(t == 255) chunksums[blockIdx.x] = lds[255];
}

__global__ void scan2_k(int* __restrict__ chunksums, int nchunks){
  __shared__ int lds[256];
  int t = threadIdx.x;
  int x = (t < nchunks) ? chunksums[t] : 0;
  lds[t] = x; __syncthreads();
  for(int o=1;o<256;o<<=1){
    int v = (t>=o) ? lds[t-o] : 0;
    __syncthreads();
    lds[t] += v;
    __syncthreads();
  }
  if(t < nchunks) chunksums[t] = lds[t] - x;   // exclusive
}

__global__ void scan3_k(const int* __restrict__ scanned, const int* __restrict__ counts,
                        const int* __restrict__ chunksums, int* __restrict__ row_start, int N){
  int i = blockIdx.x*blockDim.x + threadIdx.x;
  if(i < N) row_start[i] = scanned[i] - counts[i] + chunksums[i>>8];
}

// ---- CSR fill: single 8B record {src, norm} per edge ----
__global__ void fill_k(const int* __restrict__ src, const int* __restrict__ dst,
                       const float* __restrict__ dinv, const int* __restrict__ row_start,
                       int* __restrict__ cursor, uint2* __restrict__ csr, int E){
  int e = blockIdx.x*blockDim.x + threadIdx.x;
  if(e >= E) return;
  int d = dst[e], s = src[e];
  int pos = row_start[d] + atomicAdd(&cursor[d], 1);
  uint2 rec;
  rec.x = (unsigned)s;
  rec.y = __float_as_uint(dinv[s]*dinv[d]);
  csr[pos] = rec;
}

// ---- graph boundaries via binary search (batch is sorted) ----
__global__ void bounds_k(const int* __restrict__ batch, int* __restrict__ bound, int N, int G){
  int g = threadIdx.x;
  if(g > G) return;
  int lo = 0, hi = N;
  while(lo < hi){ int mid = (lo+hi)>>1; if(batch[mid] < g) lo = mid+1; else hi = mid; }
  bound[g] = lo;
}

// ---- W prep: f32 [k][n] -> bf16 swizzled [(k>>3)*128+n][k&7], all 3 layers ----
__global__ void wprep_k(const float* __restrict__ W0, const float* __restrict__ W1,
                        const float* __restrict__ W2, unsigned short* __restrict__ Wsw){
  int t = blockIdx.x*256 + threadIdx.x;
  if(t >= 3*16384) return;
  int l = t >> 14; int i = t & 16383;
  const float* W = (l==0) ? W0 : ((l==1) ? W1 : W2);
  int k = i >> 7, n = i & 127;
  Wsw[l*16384 + (((k>>3)*128 + n)<<3) + (k&7)] = f2bf(W[k*128+n]);
}

// ---- MFMA GEMM: Bh[N,128](bf16) = bnsig(A)[N,128] @ W[128,128] ----
__global__ __launch_bounds__(256) void gemm_mfma_k(const float* __restrict__ A,
                                                   const unsigned short* __restrict__ Wsw,
                                                   unsigned short* __restrict__ Bh,
                                                   const float* __restrict__ scale,
                                                   const float* __restrict__ shift,
                                                   int N){
  __shared__ unsigned short Al[16384];   // 32 KB
  __shared__ unsigned short Wl[16384];   // 32 KB  (total 64 KB -> 2 blocks/CU)
  int t = threadIdx.x;
  int row0 = blockIdx.x * 128;
  bool bn = (scale != nullptr);

  // stage W: 2048 x 16B coalesced copies
  #pragma unroll
  for(int i=0;i<8;i++){
    int u = t + i*256;                   // 16B-unit index
    *(uint4*)&Wl[u<<3] = *(const uint4*)&Wsw[u<<3];
  }
  // stage A: fused BN+sigmoid + bf16 pack; o = k-octet (coalesced global reads)
  int o = t & 15, rbase = t >> 4;        // 16 rows per iter
  #pragma unroll
  for(int it=0; it<8; it++){
    int r = rbase + it*16;
    int grow = row0 + r;
    float4 v0 = make_float4(0.f,0.f,0.f,0.f), v1 = v0;
    if(grow < N){
      v0 = *(const float4*)&A[grow*NDIM + o*8];
      v1 = *(const float4*)&A[grow*NDIM + o*8 + 4];
      if(bn){
        float4 sc0 = *(const float4*)&scale[o*8],   sh0 = *(const float4*)&shift[o*8];
        float4 sc1 = *(const float4*)&scale[o*8+4], sh1 = *(const float4*)&shift[o*8+4];
        v0.x = sigmoidf_(v0.x*sc0.x + sh0.x); v0.y = sigmoidf_(v0.y*sc0.y + sh0.y);
        v0.z = sigmoidf_(v0.z*sc0.z + sh0.z); v0.w = sigmoidf_(v0.w*sc0.w + sh0.w);
        v1.x = sigmoidf_(v1.x*sc1.x + sh1.x); v1.y = sigmoidf_(v1.y*sc1.y + sh1.y);
        v1.z = sigmoidf_(v1.z*sc1.z + sh1.z); v1.w = sigmoidf_(v1.w*sc1.w + sh1.w);
      }
    }
    uint4 pk;
    pk.x = (unsigned)f2bf(v0.x) | ((unsigned)f2bf(v0.y)<<16);
    pk.y = (unsigned)f2bf(v0.z) | ((unsigned)f2bf(v0.w)<<16);
    pk.z = (unsigned)f2bf(v1.x) | ((unsigned)f2bf(v1.y)<<16);
    pk.w = (unsigned)f2bf(v1.z) | ((unsigned)f2bf(v1.w)<<16);
    *(uint4*)&Al[(o*128 + r)<<3] = pk;
  }
  __syncthreads();

  int wv = t >> 6, lane = t & 63, quad = lane >> 4, l16 = lane & 15;
  int rw = (wv & 1) * 64, cw = (wv >> 1) * 64;
  f32x4 acc[4][4];
  #pragma unroll
  for(int rt=0;rt<4;rt++)
    #pragma unroll
    for(int ct=0;ct<4;ct++) acc[rt][ct] = (f32x4){0.f,0.f,0.f,0.f};

  #pragma unroll
  for(int ks=0; ks<4; ks++){
    short8 a[4], b[4];
    #pragma unroll
    for(int rt=0;rt<4;rt++)
      a[rt] = *(short8*)&Al[(((ks*4+quad)*128) + rw + rt*16 + l16) << 3];
    #pragma unroll
    for(int ct=0;ct<4;ct++)
      b[ct] = *(short8*)&Wl[(((ks*4+quad)*128) + cw + ct*16 + l16) << 3];
    #pragma unroll
    for(int rt=0;rt<4;rt++)
      #pragma unroll
      for(int ct=0;ct<4;ct++)
        acc[rt][ct] = __builtin_amdgcn_mfma_f32_16x16x32_bf16(a[rt], b[ct], acc[rt][ct], 0, 0, 0);
  }

  // epilogue: C/D layout col=lane&15, row=quad*4+reg
  #pragma unroll
  for(int rt=0;rt<4;rt++){
    int gr = row0 + rw + rt*16 + quad*4;
    #pragma unroll
    for(int ct=0;ct<4;ct++){
      int col = cw + ct*16 + l16;
      #pragma unroll
      for(int reg=0;reg<4;reg++){
        if(gr + reg < N) Bh[(gr+reg)*NDIM + col] = f2bf(acc[rt][ct][reg]);
      }
    }
  }
}

// ---- CSR gather aggregation + fused BN stats ----
// 256 threads = 4 waves; wave w handles dst row blockIdx.x*4+w.
// Full-wave row gathers (64 lanes x 4B = 256B), 4 rows in flight per wave.
__global__ __launch_bounds__(256) void agg_k(const unsigned int* __restrict__ hb,
                      const float* __restrict__ dinv,
                      const int* __restrict__ row_start, const int* __restrict__ counts,
                      const uint2* __restrict__ csr,
                      const float* __restrict__ bias, float* __restrict__ hC,
                      float* __restrict__ sums, float* __restrict__ sumsq, int N){
  __shared__ float ls[NDIM], lq[NDIM];
  int t = threadIdx.x;
  if(t < NDIM){ ls[t] = 0.f; lq[t] = 0.f; }
  __syncthreads();

  int w = t >> 6, lane = t & 63;
  int i = blockIdx.x*4 + w;
  if(i < N){
    int rs = row_start[i], re = rs + counts[i];
    float2 acc = make_float2(0.f, 0.f);
    int j = rs;
    for(; j+3 < re; j += 4){
      uint2 r0 = csr[j], r1 = csr[j+1], r2 = csr[j+2], r3 = csr[j+3];
      unsigned u0 = hb[(size_t)r0.x*64 + lane];
      unsigned u1 = hb[(size_t)r1.x*64 + lane];
      unsigned u2 = hb[(size_t)r2.x*64 + lane];
      unsigned u3 = hb[(size_t)r3.x*64 + lane];
      float n0 = __uint_as_float(r0.y), n1 = __uint_as_float(r1.y);
      float n2 = __uint_as_float(r2.y), n3 = __uint_as_float(r3.y);
      acc.x += n0*__uint_as_float(u0<<16) + n1*__uint_as_float(u1<<16)
             + n2*__uint_as_float(u2<<16) + n3*__uint_as_float(u3<<16);
      acc.y += n0*__uint_as_float(u0 & 0xffff0000u) + n1*__uint_as_float(u1 & 0xffff0000u)
             + n2*__uint_as_float(u2 & 0xffff0000u) + n3*__uint_as_float(u3 & 0xffff0000u);
    }
    for(; j < re; j++){
      uint2 r0 = csr[j];
      unsigned u0 = hb[(size_t)r0.x*64 + lane];
      float n0 = __uint_as_float(r0.y);
      acc.x += n0*__uint_as_float(u0<<16);
      acc.y += n0*__uint_as_float(u0 & 0xffff0000u);
    }
    float di = dinv[i], sn = di*di;
    unsigned su = hb[(size_t)i*64 + lane];
    float2 bv = *(const float2*)&bias[lane*2];
    float2 o;
    o.x = acc.x + sn*__uint_as_float(su<<16)           + bv.x;
    o.y = acc.y + sn*__uint_as_float(su & 0xffff0000u) + bv.y;
    *(float2*)&hC[(size_t)i*NDIM + lane*2] = o;
    // fused BN stats: features {2*lane, 2*lane+1}; 4-way LDS-atomic contention max
    atomicAdd(&ls[lane*2],   o.x);
    atomicAdd(&ls[lane*2+1], o.y);
    atomicAdd(&lq[lane*2],   o.x*o.x);
    atomicAdd(&lq[lane*2+1], o.y*o.y);
  }
  __syncthreads();
  if(t < NDIM){
    atomicAdd(&sums[t],  ls[t]);
    atomicAdd(&sumsq[t], lq[t]);
  }
}

// ---- BN finalize: per-feature scale/shift so bn_sigmoid(v) = sigmoid(v*scale+shift) ----
__global__ void finalize_k(const float* __restrict__ sums, const float* __restrict__ sumsq,
                           const float* __restrict__ g, const float* __restrict__ be,
                           float* __restrict__ scale, float* __restrict__ shift, int N){
  int f = threadIdx.x;   // 128
  float invN = 1.0f/(float)N;
  float m = sums[f]*invN;
  float var = fmaxf(sumsq[f]*invN - m*m, 0.f);
  float s = g[f]*rsqrtf(var + 1e-5f);
  scale[f] = s;
  shift[f] = be[f] - m*s;
}

// ---- pooling phase 1: chunked segment-sum of sigmoid(v*scale+shift) ----
#define PCH 128
__global__ __launch_bounds__(256) void pool_k(const float* __restrict__ hC,
                                              const int* __restrict__ batch,
                                              const float* __restrict__ scale,
                                              const float* __restrict__ shift,
                                              float* __restrict__ out, int N){
  int t = threadIdx.x;
  int f = t & 127, half = t >> 7;
  int r0 = blockIdx.x*PCH + half;
  int r1 = min(N, blockIdx.x*PCH + PCH);
  float sc = scale[f], sh = shift[f];
  float acc = 0.f; int cur = -1;
  for(int r = r0; r < r1; r += 2){
    int g = batch[r];
    if(g != cur){
      if(cur >= 0) atomicAdd(&out[cur*NDIM + f], acc);
      acc = 0.f; cur = g;
    }
    acc += sigmoidf_(hC[r*NDIM + f]*sc + sh);
  }
  if(cur >= 0) atomicAdd(&out[cur*NDIM + f], acc);
}

// ---- pooling phase 2: divide by graph size ----
__global__ void div_k(float* __restrict__ out, const int* __restrict__ bound){
  int g = blockIdx.x, f = threadIdx.x;
  float cnt = (float)(bound[g+1] - bound[g]);
  out[g*NDIM + f] /= fmaxf(cnt, 1.0f);
}

extern "C" void kernel_launch(void* const* d_in, const int* in_sizes, int n_in,
                              void* d_out, int out_size, void* d_ws, size_t ws_size,
                              hipStream_t stream){
  const float* x     = (const float*)d_in[0];
  const int*   ei    = (const int*)d_in[1];
  const int*   batch = (const int*)d_in[3];
  const float* W [3] = {(const float*)d_in[4], (const float*)d_in[6], (const float*)d_in[8]};
  const float* bi[3] = {(const float*)d_in[5], (const float*)d_in[7], (const float*)d_in[9]};
  const float* gg[3] = {(const float*)d_in[10], (const float*)d_in[12], (const float*)d_in[14]};
  const float* bb[3] = {(const float*)d_in[11], (const float*)d_in[13], (const float*)d_in[15]};

  int N = in_sizes[0] / NDIM;
  int E = in_sizes[1] / 2;
  int G = out_size / NDIM;
  const int* src = ei;
  const int* dst = ei + E;

  // workspace bump allocator (256 B aligned)
  char* p = (char*)d_ws;
  auto alloc = [&](size_t bytes)->void*{
    void* r = (void*)p; p += (bytes + 255) & ~(size_t)255; return r;
  };
  unsigned short* hB  = (unsigned short*)alloc((size_t)N*NDIM*2);   // bf16
  unsigned short* Wsw = (unsigned short*)alloc(3*16384*2);          // bf16 swizzled weights
  float* hC        = (float*)alloc((size_t)N*NDIM*4);
  int*   counts    = (int*)  alloc((size_t)N*4);
  int*   cursor    = (int*)  alloc((size_t)N*4);
  int*   scanned   = (int*)  alloc((size_t)N*4);
  int*   chunksums = (int*)  alloc(256*4);
  int*   row_start = (int*)  alloc((size_t)N*4);
  float* dinv      = (float*)alloc((size_t)N*4);
  uint2* csr       = (uint2*)alloc((size_t)E*8);
  float* sums      = (float*)alloc(3*128*4);
  float* sumsq     = (float*)alloc(3*128*4);
  float* scale     = (float*)alloc(3*128*4);
  float* shift     = (float*)alloc(3*128*4);
  int*   bound     = (int*)  alloc(256*4);

  hipMemsetAsync(counts, 0, (size_t)N*4, stream);
  hipMemsetAsync(cursor, 0, (size_t)N*4, stream);
  hipMemsetAsync(sums,  0, 3*128*4, stream);
  hipMemsetAsync(sumsq, 0, 3*128*4, stream);
  hipMemsetAsync(d_out, 0, (size_t)out_size*4, stream);

  deg_count_k<<<(E+255)/256, 256, 0, stream>>>(dst, counts, E);
  dinv_k<<<(N+255)/256, 256, 0, stream>>>(counts, dinv, N);

  int nchunks = (N+255)/256;     // 196 <= 256
  scan1_k<<<nchunks, 256, 0, stream>>>(counts, scanned, chunksums, N);
  scan2_k<<<1, 256, 0, stream>>>(chunksums, nchunks);
  scan3_k<<<(N+255)/256, 256, 0, stream>>>(scanned, counts, chunksums, row_start, N);
  fill_k<<<(E+255)/256, 256, 0, stream>>>(src, dst, dinv, row_start, cursor, csr, E);
  bounds_k<<<1, 128, 0, stream>>>(batch, bound, N, G);
  wprep_k<<<(3*16384+255)/256, 256, 0, stream>>>(W[0], W[1], W[2], Wsw);

  const float* hin = x;
  for(int l=0; l<3; l++){
    const float* sc = (l == 0) ? nullptr : (scale + (l-1)*128);
    const float* sh = (l == 0) ? nullptr : (shift + (l-1)*128);
    gemm_mfma_k<<<(N+127)/128, 256, 0, stream>>>(hin, Wsw + l*16384, hB, sc, sh, N);
    agg_k<<<(N+3)/4, 256, 0, stream>>>((const unsigned int*)hB, dinv, row_start, counts,
                                       csr, bi[l], hC, sums + l*128, sumsq + l*128, N);
    finalize_k<<<1, 128, 0, stream>>>(sums + l*128, sumsq + l*128, gg[l], bb[l],
                                      scale + l*128, shift + l*128, N);
    hin = hC;
  }

  pool_k<<<(N+PCH-1)/PCH, 256, 0, stream>>>(hC, batch, scale + 2*128, shift + 2*128,
                                            (float*)d_out, N);
  div_k<<<G, 128, 0, stream>>>((float*)d_out, bound);
}

// Round 7
// 474.200 us; speedup vs baseline: 2.7040x; 2.7040x over previous
//
#include <hip/hip_runtime.h>
#include <math.h>

#define NDIM 128      // feature dim (D == H == 128)

typedef __attribute__((ext_vector_type(8))) short short8;
typedef __attribute__((ext_vector_type(4))) float f32x4;

__device__ __forceinline__ float sigmoidf_(float x){ return 1.0f/(1.0f + __expf(-x)); }

// f32 -> bf16 (round-to-nearest-even)
__device__ __forceinline__ unsigned short f2bf(float f){
  unsigned u = __float_as_uint(f);
  unsigned r = (u + 0x7fffu + ((u >> 16) & 1u)) >> 16;
  return (unsigned short)r;
}

// ---- degree ----
__global__ void deg_count_k(const int* __restrict__ dst, int* __restrict__ counts, int E){
  int e = blockIdx.x*blockDim.x + threadIdx.x;
  if(e < E) atomicAdd(&counts[dst[e]], 1);
}

// ---- 3-kernel exclusive prefix scan over counts (chunk = 256) ----
__global__ void scan1_k(const int* __restrict__ counts, int* __restrict__ scanned,
                        int* __restrict__ chunksums, int N){
  __shared__ int lds[256];
  int t = threadIdx.x; int idx = blockIdx.x*256 + t;
  int x = (idx < N) ? counts[idx] : 0;
  lds[t] = x; __syncthreads();
  for(int o=1;o<256;o<<=1){
    int v = (t>=o) ? lds[t-o] : 0;
    __syncthreads();
    lds[t] += v;
    __syncthreads();
  }
  if(idx < N) scanned[idx] = lds[t];
  if(t == 255) chunksums[blockIdx.x] = lds[255];
}

__global__ void scan2_k(int* __restrict__ chunksums, int nchunks){
  __shared__ int lds[256];
  int t = threadIdx.x;
  int x = (t < nchunks) ? chunksums[t] : 0;
  lds[t] = x; __syncthreads();
  for(int o=1;o<256;o<<=1){
    int v = (t>=o) ? lds[t-o] : 0;
    __syncthreads();
    lds[t] += v;
    __syncthreads();
  }
  if(t < nchunks) chunksums[t] = lds[t] - x;   // exclusive
}

// scan3 + dinv fused (both only need counts)
__global__ void scan3_k(const int* __restrict__ scanned, const int* __restrict__ counts,
                        const int* __restrict__ chunksums, int* __restrict__ row_start,
                        float* __restrict__ dinv, int N){
  int i = blockIdx.x*blockDim.x + threadIdx.x;
  if(i < N){
    row_start[i] = scanned[i] - counts[i] + chunksums[i>>8];
    dinv[i] = rsqrtf(1.0f + (float)counts[i]);
  }
}

// ---- CSR fill: single 8B record {src, norm} per edge ----
__global__ void fill_k(const int* __restrict__ src, const int* __restrict__ dst,
                       const float* __restrict__ dinv, const int* __restrict__ row_start,
                       int* __restrict__ cursor, uint2* __restrict__ csr, int E){
  int e = blockIdx.x*blockDim.x + threadIdx.x;
  if(e >= E) return;
  int d = dst[e], s = src[e];
  int pos = row_start[d] + atomicAdd(&cursor[d], 1);
  uint2 rec;
  rec.x = (unsigned)s;
  rec.y = __float_as_uint(dinv[s]*dinv[d]);
  csr[pos] = rec;
}

// ---- graph boundaries via binary search (batch is sorted) ----
__global__ void bounds_k(const int* __restrict__ batch, int* __restrict__ bound, int N, int G){
  int g = threadIdx.x;
  if(g > G) return;
  int lo = 0, hi = N;
  while(lo < hi){ int mid = (lo+hi)>>1; if(batch[mid] < g) lo = mid+1; else hi = mid; }
  bound[g] = lo;
}

// ---- W prep: f32 [k][n] -> bf16 swizzled [(k>>3)*128+n][k&7], all 3 layers ----
__global__ void wprep_k(const float* __restrict__ W0, const float* __restrict__ W1,
                        const float* __restrict__ W2, unsigned short* __restrict__ Wsw){
  int t = blockIdx.x*256 + threadIdx.x;
  if(t >= 3*16384) return;
  int l = t >> 14; int i = t & 16383;
  const float* W = (l==0) ? W0 : ((l==1) ? W1 : W2);
  int k = i >> 7, n = i & 127;
  Wsw[l*16384 + (((k>>3)*128 + n)<<3) + (k&7)] = f2bf(W[k*128+n]);
}

// ---- MFMA GEMM: Bh[N,128](bf16) = bnsig(A)[N,128] @ W[128,128] ----
__global__ __launch_bounds__(256) void gemm_mfma_k(const float* __restrict__ A,
                                                   const unsigned short* __restrict__ Wsw,
                                                   unsigned short* __restrict__ Bh,
                                                   const float* __restrict__ scale,
                                                   const float* __restrict__ shift,
                                                   int N){
  __shared__ unsigned short Al[16384];   // 32 KB
  __shared__ unsigned short Wl[16384];   // 32 KB  (total 64 KB -> 2 blocks/CU)
  int t = threadIdx.x;
  int row0 = blockIdx.x * 128;
  bool bn = (scale != nullptr);

  // stage W: 2048 x 16B coalesced copies
  #pragma unroll
  for(int i=0;i<8;i++){
    int u = t + i*256;                   // 16B-unit index
    *(uint4*)&Wl[u<<3] = *(const uint4*)&Wsw[u<<3];
  }
  // stage A: fused BN+sigmoid + bf16 pack; o = k-octet (coalesced global reads)
  int o = t & 15, rbase = t >> 4;        // 16 rows per iter
  #pragma unroll
  for(int it=0; it<8; it++){
    int r = rbase + it*16;
    int grow = row0 + r;
    float4 v0 = make_float4(0.f,0.f,0.f,0.f), v1 = v0;
    if(grow < N){
      v0 = *(const float4*)&A[grow*NDIM + o*8];
      v1 = *(const float4*)&A[grow*NDIM + o*8 + 4];
      if(bn){
        float4 sc0 = *(const float4*)&scale[o*8],   sh0 = *(const float4*)&shift[o*8];
        float4 sc1 = *(const float4*)&scale[o*8+4], sh1 = *(const float4*)&shift[o*8+4];
        v0.x = sigmoidf_(v0.x*sc0.x + sh0.x); v0.y = sigmoidf_(v0.y*sc0.y + sh0.y);
        v0.z = sigmoidf_(v0.z*sc0.z + sh0.z); v0.w = sigmoidf_(v0.w*sc0.w + sh0.w);
        v1.x = sigmoidf_(v1.x*sc1.x + sh1.x); v1.y = sigmoidf_(v1.y*sc1.y + sh1.y);
        v1.z = sigmoidf_(v1.z*sc1.z + sh1.z); v1.w = sigmoidf_(v1.w*sc1.w + sh1.w);
      }
    }
    uint4 pk;
    pk.x = (unsigned)f2bf(v0.x) | ((unsigned)f2bf(v0.y)<<16);
    pk.y = (unsigned)f2bf(v0.z) | ((unsigned)f2bf(v0.w)<<16);
    pk.z = (unsigned)f2bf(v1.x) | ((unsigned)f2bf(v1.y)<<16);
    pk.w = (unsigned)f2bf(v1.z) | ((unsigned)f2bf(v1.w)<<16);
    *(uint4*)&Al[(o*128 + r)<<3] = pk;
  }
  __syncthreads();

  int wv = t >> 6, lane = t & 63, quad = lane >> 4, l16 = lane & 15;
  int rw = (wv & 1) * 64, cw = (wv >> 1) * 64;
  f32x4 acc[4][4];
  #pragma unroll
  for(int rt=0;rt<4;rt++)
    #pragma unroll
    for(int ct=0;ct<4;ct++) acc[rt][ct] = (f32x4){0.f,0.f,0.f,0.f};

  #pragma unroll
  for(int ks=0; ks<4; ks++){
    short8 a[4], b[4];
    #pragma unroll
    for(int rt=0;rt<4;rt++)
      a[rt] = *(short8*)&Al[(((ks*4+quad)*128) + rw + rt*16 + l16) << 3];
    #pragma unroll
    for(int ct=0;ct<4;ct++)
      b[ct] = *(short8*)&Wl[(((ks*4+quad)*128) + cw + ct*16 + l16) << 3];
    #pragma unroll
    for(int rt=0;rt<4;rt++)
      #pragma unroll
      for(int ct=0;ct<4;ct++)
        acc[rt][ct] = __builtin_amdgcn_mfma_f32_16x16x32_bf16(a[rt], b[ct], acc[rt][ct], 0, 0, 0);
  }

  // epilogue: C/D layout col=lane&15, row=quad*4+reg
  #pragma unroll
  for(int rt=0;rt<4;rt++){
    int gr = row0 + rw + rt*16 + quad*4;
    #pragma unroll
    for(int ct=0;ct<4;ct++){
      int col = cw + ct*16 + l16;
      #pragma unroll
      for(int reg=0;reg<4;reg++){
        if(gr + reg < N) Bh[(gr+reg)*NDIM + col] = f2bf(acc[rt][ct][reg]);
      }
    }
  }
}

// ---- CSR gather aggregation: one 64-thread wave per dst row, pure gather ----
__global__ void agg_k(const unsigned int* __restrict__ hb,
                      const float* __restrict__ dinv,
                      const int* __restrict__ row_start, const int* __restrict__ counts,
                      const uint2* __restrict__ csr,
                      const float* __restrict__ bias, float* __restrict__ hC, int N){
  int i = blockIdx.x;
  if(i >= N) return;
  int lane = threadIdx.x;            // 64 lanes, lane = feature pair (uint = 2 bf16)
  int rs = row_start[i], re = rs + counts[i];
  float ax = 0.f, ay = 0.f;
  int j = rs;
  for(; j+3 < re; j += 4){           // 4 row-gathers in flight
    uint2 r0 = csr[j], r1 = csr[j+1], r2 = csr[j+2], r3 = csr[j+3];
    unsigned u0 = hb[(size_t)r0.x*64 + lane];
    unsigned u1 = hb[(size_t)r1.x*64 + lane];
    unsigned u2 = hb[(size_t)r2.x*64 + lane];
    unsigned u3 = hb[(size_t)r3.x*64 + lane];
    float n0 = __uint_as_float(r0.y), n1 = __uint_as_float(r1.y);
    float n2 = __uint_as_float(r2.y), n3 = __uint_as_float(r3.y);
    ax += n0*__uint_as_float(u0<<16) + n1*__uint_as_float(u1<<16)
        + n2*__uint_as_float(u2<<16) + n3*__uint_as_float(u3<<16);
    ay += n0*__uint_as_float(u0 & 0xffff0000u) + n1*__uint_as_float(u1 & 0xffff0000u)
        + n2*__uint_as_float(u2 & 0xffff0000u) + n3*__uint_as_float(u3 & 0xffff0000u);
  }
  for(; j < re; j++){
    uint2 r0 = csr[j];
    unsigned u0 = hb[(size_t)r0.x*64 + lane];
    float n0 = __uint_as_float(r0.y);
    ax += n0*__uint_as_float(u0<<16);
    ay += n0*__uint_as_float(u0 & 0xffff0000u);
  }
  float di = dinv[i], sn = di*di;
  unsigned su = hb[(size_t)i*64 + lane];
  float2 bv = *(const float2*)&bias[lane*2];
  float2 o;
  o.x = ax + sn*__uint_as_float(su<<16)           + bv.x;
  o.y = ay + sn*__uint_as_float(su & 0xffff0000u) + bv.y;
  *(float2*)&hC[(size_t)i*NDIM + lane*2] = o;
}

// ---- BN column stats (sum, sumsq); 400 blocks => ~102k global atomics ----
__global__ void stats_k(const float* __restrict__ h, float* __restrict__ sums,
                        float* __restrict__ sumsq, int N){
  __shared__ float ls[256], lq[256];
  int t = threadIdx.x;
  int f = t & 127, half = t >> 7;
  int rowsPerBlock = (N + gridDim.x - 1)/gridDim.x;
  int r0 = blockIdx.x * rowsPerBlock;
  int r1 = min(N, r0 + rowsPerBlock);
  float s=0.f, q=0.f;
  for(int r=r0+half; r<r1; r+=2){
    float v = h[r*NDIM + f];
    s += v; q += v*v;
  }
  ls[t]=s; lq[t]=q; __syncthreads();
  if(t < 128){
    s = ls[t] + ls[t+128];
    q = lq[t] + lq[t+128];
    atomicAdd(&sums[f], s);
    atomicAdd(&sumsq[f], q);
  }
}

// ---- BN finalize: per-feature scale/shift so bn_sigmoid(v) = sigmoid(v*scale+shift) ----
__global__ void finalize_k(const float* __restrict__ sums, const float* __restrict__ sumsq,
                           const float* __restrict__ g, const float* __restrict__ be,
                           float* __restrict__ scale, float* __restrict__ shift, int N){
  int f = threadIdx.x;   // 128
  float invN = 1.0f/(float)N;
  float m = sums[f]*invN;
  float var = fmaxf(sumsq[f]*invN - m*m, 0.f);
  float s = g[f]*rsqrtf(var + 1e-5f);
  scale[f] = s;
  shift[f] = be[f] - m*s;
}

// ---- pooling phase 1: chunked segment-sum of sigmoid(v*scale+shift) ----
#define PCH 128
__global__ __launch_bounds__(256) void pool_k(const float* __restrict__ hC,
                                              const int* __restrict__ batch,
                                              const float* __restrict__ scale,
                                              const float* __restrict__ shift,
                                              float* __restrict__ out, int N){
  int t = threadIdx.x;
  int f = t & 127, half = t >> 7;
  int r0 = blockIdx.x*PCH + half;
  int r1 = min(N, blockIdx.x*PCH + PCH);
  float sc = scale[f], sh = shift[f];
  float acc = 0.f; int cur = -1;
  for(int r = r0; r < r1; r += 2){
    int g = batch[r];
    if(g != cur){
      if(cur >= 0) atomicAdd(&out[cur*NDIM + f], acc);
      acc = 0.f; cur = g;
    }
    acc += sigmoidf_(hC[r*NDIM + f]*sc + sh);
  }
  if(cur >= 0) atomicAdd(&out[cur*NDIM + f], acc);
}

// ---- pooling phase 2: divide by graph size ----
__global__ void div_k(float* __restrict__ out, const int* __restrict__ bound){
  int g = blockIdx.x, f = threadIdx.x;
  float cnt = (float)(bound[g+1] - bound[g]);
  out[g*NDIM + f] /= fmaxf(cnt, 1.0f);
}

extern "C" void kernel_launch(void* const* d_in, const int* in_sizes, int n_in,
                              void* d_out, int out_size, void* d_ws, size_t ws_size,
                              hipStream_t stream){
  const float* x     = (const float*)d_in[0];
  const int*   ei    = (const int*)d_in[1];
  const int*   batch = (const int*)d_in[3];
  const float* W [3] = {(const float*)d_in[4], (const float*)d_in[6], (const float*)d_in[8]};
  const float* bi[3] = {(const float*)d_in[5], (const float*)d_in[7], (const float*)d_in[9]};
  const float* gg[3] = {(const float*)d_in[10], (const float*)d_in[12], (const float*)d_in[14]};
  const float* bb[3] = {(const float*)d_in[11], (const float*)d_in[13], (const float*)d_in[15]};

  int N = in_sizes[0] / NDIM;
  int E = in_sizes[1] / 2;
  int G = out_size / NDIM;
  const int* src = ei;
  const int* dst = ei + E;

  // workspace bump allocator (256 B aligned)
  char* p = (char*)d_ws;
  auto alloc = [&](size_t bytes)->void*{
    void* r = (void*)p; p += (bytes + 255) & ~(size_t)255; return r;
  };
  unsigned short* hB  = (unsigned short*)alloc((size_t)N*NDIM*2);   // bf16
  unsigned short* Wsw = (unsigned short*)alloc(3*16384*2);          // bf16 swizzled weights
  float* hC        = (float*)alloc((size_t)N*NDIM*4);
  int*   counts    = (int*)  alloc((size_t)2*N*4);  // counts[N] + cursor[N], one memset
  int*   cursor    = counts + N;
  int*   scanned   = (int*)  alloc((size_t)N*4);
  int*   chunksums = (int*)  alloc(256*4);
  int*   row_start = (int*)  alloc((size_t)N*4);
  float* dinv      = (float*)alloc((size_t)N*4);
  uint2* csr       = (uint2*)alloc((size_t)E*8);
  float* sums      = (float*)alloc(2*3*128*4);      // sums[3][128] + sumsq[3][128], one memset
  float* sumsq     = sums + 3*128;
  float* scale     = (float*)alloc(3*128*4);
  float* shift     = (float*)alloc(3*128*4);
  int*   bound     = (int*)  alloc(256*4);

  hipMemsetAsync(counts, 0, (size_t)2*N*4, stream);
  hipMemsetAsync(sums,  0, 2*3*128*4, stream);
  hipMemsetAsync(d_out, 0, (size_t)out_size*4, stream);

  deg_count_k<<<(E+255)/256, 256, 0, stream>>>(dst, counts, E);

  int nchunks = (N+255)/256;     // 196 <= 256
  scan1_k<<<nchunks, 256, 0, stream>>>(counts, scanned, chunksums, N);
  scan2_k<<<1, 256, 0, stream>>>(chunksums, nchunks);
  scan3_k<<<(N+255)/256, 256, 0, stream>>>(scanned, counts, chunksums, row_start, dinv, N);
  fill_k<<<(E+255)/256, 256, 0, stream>>>(src, dst, dinv, row_start, cursor, csr, E);
  bounds_k<<<1, 128, 0, stream>>>(batch, bound, N, G);
  wprep_k<<<(3*16384+255)/256, 256, 0, stream>>>(W[0], W[1], W[2], Wsw);

  const float* hin = x;
  for(int l=0; l<3; l++){
    const float* sc = (l == 0) ? nullptr : (scale + (l-1)*128);
    const float* sh = (l == 0) ? nullptr : (shift + (l-1)*128);
    gemm_mfma_k<<<(N+127)/128, 256, 0, stream>>>(hin, Wsw + l*16384, hB, sc, sh, N);
    agg_k<<<N, 64, 0, stream>>>((const unsigned int*)hB, dinv, row_start, counts,
                                csr, bi[l], hC, N);
    stats_k<<<400, 256, 0, stream>>>(hC, sums + l*128, sumsq + l*128, N);
    finalize_k<<<1, 128, 0, stream>>>(sums + l*128, sumsq + l*128, gg[l], bb[l],
                                      scale + l*128, shift + l*128, N);
    hin = hC;
  }

  pool_k<<<(N+PCH-1)/PCH, 256, 0, stream>>>(hC, batch, scale + 2*128, shift + 2*128,
                                            (float*)d_out, N);
  div_k<<<G, 128, 0, stream>>>((float*)d_out, bound);
}